// Round 8
// baseline (577.363 us; speedup 1.0000x reference)
//
#include <hip/hip_runtime.h>

typedef _Float16 f16;
typedef _Float16 half8 __attribute__((ext_vector_type(8)));
typedef _Float16 half4 __attribute__((ext_vector_type(4)));
typedef float    f32x4 __attribute__((ext_vector_type(4)));

#define DEV static __device__ __forceinline__

constexpr int NB = 8, CH = 512, HW = 4096, IH = 64, IW = 64;

typedef const __attribute__((address_space(1))) void gas_void;
typedef __attribute__((address_space(3))) void       las_void;

// ---- async staging: f16 global [rows][ld] -> linear LDS [rows][64] ----
template <int ROWS>
DEV void stage_gll(f16* lds, const f16* src, long ld) {
  const int lane = threadIdx.x & 63, w = threadIdx.x >> 6;
  const int r8 = lane >> 3, c16 = lane & 7;
#pragma unroll
  for (int i = w; i < (ROWS / 8); i += 4) {
    const f16* g = src + (long)(i * 8 + r8) * ld + c16 * 8;
    __builtin_amdgcn_global_load_lds((gas_void*)g, (las_void*)(lds + i * 512 + lane * 8), 16, 0, 0);
  }
}

// ---------------- m97-style MFMA GEMM ----------------
// O = A(MxK)*B(KxN); A,B staged [outdim][k] f16 (hi + optional lo split).
// C/D frag mapping: col = lane&15, row = (lane>>4)*4 + j  [verified m89/m91].
// EPI: 0 = split f16 write (O1 hi, O2 lo); 1 = f32 + rank1(e0*e1 + e2*e3);
//      2 = f16; 6 = f32 store into per-ks partial buffer (split-K, no atomics).
// MINW: min waves/EU hint (= blocks/CU for 256-thread blocks).
template <int BM, int BN, bool SPLIT, int KS, int EPI, int MINW>
__global__ __launch_bounds__(256, MINW) void gemm2(
    const f16* __restrict__ Ah, const f16* __restrict__ Al, long sAb, int lda,
    const f16* __restrict__ Bh, const f16* __restrict__ Bl, long sBb, int ldb,
    void* __restrict__ O1, void* __restrict__ O2, long sOb, int ldo, int K,
    const float* __restrict__ e0, const float* __restrict__ e1,
    const float* __restrict__ e2, const float* __restrict__ e3) {
  constexpr int FM = BM / 32, FN = BN / 32;
  __shared__ f16 sAh[BM * 64], sBh[BN * 64];
  __shared__ f16 sAl[SPLIT ? BM * 64 : 1], sBl[SPLIT ? BN * 64 : 1];

  const int bx = blockIdx.x, by = blockIdx.y;
  const int bz = blockIdx.z, b = bz / KS, ks = bz % KS;
  const int m0 = bx * BM, n0 = by * BN;
  const int lane = threadIdx.x & 63, wave = threadIdx.x >> 6;
  const int wr = (wave >> 1) * (BM / 2), wc = (wave & 1) * (BN / 2);
  const int fr = lane & 15, fq = lane >> 4;

  const f16* Ab  = Ah + b * sAb + (long)m0 * lda;
  const f16* Bb  = Bh + b * sBb + (long)n0 * ldb;
  const f16* Ab2 = SPLIT ? Al + b * sAb + (long)m0 * lda : nullptr;
  const f16* Bb2 = SPLIT ? Bl + b * sBb + (long)n0 * ldb : nullptr;

  f32x4 acc[FM][FN] = {};
  const int kbeg = ks * K, kend = kbeg + K;
  for (int k0 = kbeg; k0 < kend; k0 += 64) {
    stage_gll<BM>(sAh, Ab + k0, lda);
    stage_gll<BN>(sBh, Bb + k0, ldb);
    if constexpr (SPLIT) {
      stage_gll<BM>(sAl, Ab2 + k0, lda);
      stage_gll<BN>(sBl, Bb2 + k0, ldb);
    }
    __syncthreads();
#pragma unroll
    for (int kk = 0; kk < 2; ++kk) {
      half8 ah[FM], bh[FN];
#pragma unroll
      for (int mi = 0; mi < FM; ++mi)
        ah[mi] = *(const half8*)&sAh[(wr + mi * 16 + fr) * 64 + kk * 32 + fq * 8];
#pragma unroll
      for (int ni = 0; ni < FN; ++ni)
        bh[ni] = *(const half8*)&sBh[(wc + ni * 16 + fr) * 64 + kk * 32 + fq * 8];
      if constexpr (SPLIT) {
        half8 al[FM], bl[FN];
#pragma unroll
        for (int mi = 0; mi < FM; ++mi)
          al[mi] = *(const half8*)&sAl[(wr + mi * 16 + fr) * 64 + kk * 32 + fq * 8];
#pragma unroll
        for (int ni = 0; ni < FN; ++ni)
          bl[ni] = *(const half8*)&sBl[(wc + ni * 16 + fr) * 64 + kk * 32 + fq * 8];
#pragma unroll
        for (int mi = 0; mi < FM; ++mi)
#pragma unroll
          for (int ni = 0; ni < FN; ++ni) {
            acc[mi][ni] = __builtin_amdgcn_mfma_f32_16x16x32_f16(ah[mi], bh[ni], acc[mi][ni], 0, 0, 0);
            acc[mi][ni] = __builtin_amdgcn_mfma_f32_16x16x32_f16(ah[mi], bl[ni], acc[mi][ni], 0, 0, 0);
            acc[mi][ni] = __builtin_amdgcn_mfma_f32_16x16x32_f16(al[mi], bh[ni], acc[mi][ni], 0, 0, 0);
          }
      } else {
#pragma unroll
        for (int mi = 0; mi < FM; ++mi)
#pragma unroll
          for (int ni = 0; ni < FN; ++ni)
            acc[mi][ni] = __builtin_amdgcn_mfma_f32_16x16x32_f16(ah[mi], bh[ni], acc[mi][ni], 0, 0, 0);
      }
    }
    __syncthreads();
  }

#pragma unroll
  for (int mi = 0; mi < FM; ++mi)
#pragma unroll
    for (int ni = 0; ni < FN; ++ni)
#pragma unroll
      for (int j = 0; j < 4; ++j) {
        const int row = m0 + wr + mi * 16 + fq * 4 + j;
        const int col = n0 + wc + ni * 16 + fr;
        float g = acc[mi][ni][j];
        const long oi = b * sOb + (long)row * ldo + col;
        if constexpr (EPI == 0) {
          f16 h = (f16)g;
          ((f16*)O1)[oi] = h;
          ((f16*)O2)[oi] = (f16)(g - (float)h);
        } else if constexpr (EPI == 1) {
          g += e0[row] * e1[b * CH + col] + e2[b * CH + row] * e3[col];
          ((float*)O1)[oi] = g;
        } else if constexpr (EPI == 2) {
          ((f16*)O1)[oi] = (f16)g;
        } else {  // EPI == 6: split-K partial, per-ks buffer
          ((float*)O1)[(((long)ks * NB + b) * CH + row) * CH + col] = g;
        }
      }
}

// ---------------- fused den-GEMM + dwconv + residual ----------------
// den = M(CHxCH) * xT tile (128 chan x 128 pix = 2 image rows);
// out = x + 0.1*(den + ab3[c] + dwconv3x3(xh) + bg[c]).
// Epilogue runs in 2 channel-halves so xdw is 64ch (33.8 KB) -> 4 blocks/CU.
__global__ __launch_bounds__(256, 4) void gemm_dw(
    const f16* __restrict__ M16, const f16* __restrict__ xT, const f16* __restrict__ xh,
    const float* __restrict__ x, const float* __restrict__ wg, const float* __restrict__ bg,
    const float* __restrict__ ab3, float* __restrict__ out) {
  __shared__ __align__(16) char smem[64 * 4 * 66 * 2];  // 33792 B: stage(32K) U xdw-half
  __shared__ float swg[128][10];
  __shared__ float sbb[128];
  f16* sA  = (f16*)smem;                   // 128*64 halves = 16 KB
  f16* sB  = (f16*)(smem + 128 * 64 * 2);  // +16 KB = 32 KB <= 33792
  f16* xdw = (f16*)smem;

  const int b = blockIdx.z;
  const int c0 = blockIdx.x * 128, p0 = blockIdx.y * 128;
  const int h0 = p0 >> 6;  // first of the 2 image rows this tile covers
  const int lane = threadIdx.x & 63, wave = threadIdx.x >> 6;
  const int wr = (wave >> 1) * 64, wc = (wave & 1) * 64;
  const int fr = lane & 15, fq = lane >> 4;
  const long CC = (long)CH * CH, CHW = (long)CH * HW;

  // prologue: weights + fused bias into LDS (consumed after K-loop)
  for (int q = threadIdx.x; q < 128 * 9; q += 256)
    swg[q / 9][q % 9] = wg[(c0 + q / 9) * 9 + q % 9];
  for (int c = threadIdx.x; c < 128; c += 256)
    sbb[c] = bg[c0 + c] + ab3[b * CH + c0 + c];

  const f16* Ab = M16 + b * CC + (long)c0 * CH;
  const f16* Bb = xT + b * CHW + (long)p0 * CH;

  f32x4 acc[4][4] = {};
  for (int k0 = 0; k0 < CH; k0 += 64) {
    stage_gll<128>(sA, Ab + k0, CH);
    stage_gll<128>(sB, Bb + k0, CH);
    __syncthreads();
#pragma unroll
    for (int kk = 0; kk < 2; ++kk) {
      half8 ah[4], bh[4];
#pragma unroll
      for (int mi = 0; mi < 4; ++mi)
        ah[mi] = *(const half8*)&sA[(wr + mi * 16 + fr) * 64 + kk * 32 + fq * 8];
#pragma unroll
      for (int ni = 0; ni < 4; ++ni)
        bh[ni] = *(const half8*)&sB[(wc + ni * 16 + fr) * 64 + kk * 32 + fq * 8];
#pragma unroll
      for (int mi = 0; mi < 4; ++mi)
#pragma unroll
        for (int ni = 0; ni < 4; ++ni)
          acc[mi][ni] = __builtin_amdgcn_mfma_f32_16x16x32_f16(ah[mi], bh[ni], acc[mi][ni], 0, 0, 0);
    }
    __syncthreads();
  }

  // epilogue: 2 rounds of 64 channels; waves wr==r*64 compute in round r
  for (int r = 0; r < 2; ++r) {
    __syncthreads();  // prev round's reads (or K-loop) done before overwrite
    for (int q = threadIdx.x; q < 64 * 4 * 16; q += 256) {
      const int c = q >> 6, dy = (q >> 4) & 3, w4 = (q & 15) * 4;
      const int hg = h0 - 1 + dy;
      half4 v = {};
      if (hg >= 0 && hg < IH)
        v = *(const half4*)(xh + ((long)b * CH + c0 + r * 64 + c) * HW + hg * 64 + w4);
      *(half4*)&xdw[(c * 4 + dy) * 66 + w4] = v;
    }
    __syncthreads();
    if ((wr >> 6) == r) {
#pragma unroll
      for (int mi = 0; mi < 4; ++mi)
#pragma unroll
        for (int j = 0; j < 4; ++j) {
          const int cl = mi * 16 + fq * 4 + j;   // local channel 0..63
          const int ci = r * 64 + cl;            // tile channel
          float wgt[9];
#pragma unroll
          for (int k = 0; k < 9; ++k) wgt[k] = swg[ci][k];
          const float bb = sbb[ci];
          const long rowbase = ((long)b * CH + c0 + ci) * HW + p0;
#pragma unroll
          for (int ni = 0; ni < 4; ++ni) {
            const int px = wc + ni * 16 + fr;
            const int h = px >> 6, w = px & 63;
            float dw = 0.f;
#pragma unroll
            for (int dy = 0; dy < 3; ++dy)
#pragma unroll
              for (int dx = 0; dx < 3; ++dx) {
                const int wx = w + dx - 1;
                const float tap =
                    (wx >= 0 && wx < IW) ? (float)xdw[(cl * 4 + h + dy) * 66 + wx] : 0.f;
                dw += wgt[dy * 3 + dx] * tap;
              }
            const float xv = x[rowbase + px];
            out[rowbase + px] = xv + 0.1f * (acc[mi][ni][j] + bb + dw);
          }
        }
    }
  }
}

// ---------------- reductions ----------------
template <int OP>  // 0 = sum, 1 = max
DEV float blockReduce(float v) {
#pragma unroll
  for (int o = 32; o; o >>= 1) {
    float w = __shfl_xor(v, o);
    v = OP ? fmaxf(v, w) : v + w;
  }
  __shared__ float t[4];
  __shared__ float res;
  __syncthreads();
  if ((threadIdx.x & 63) == 0) t[threadIdx.x >> 6] = v;
  __syncthreads();
  if (threadIdx.x == 0)
    res = OP ? fmaxf(fmaxf(t[0], t[1]), fmaxf(t[2], t[3])) : t[0] + t[1] + t[2] + t[3];
  __syncthreads();
  return res;
}

// ---------------- prep / small kernels ----------------
// x (f32 row) -> xh = f16(x), xm = f16(2x - xh)  + exact full-row sum -> sv
__global__ __launch_bounds__(256) void convert1(const float* __restrict__ x, f16* __restrict__ xh,
                                                f16* __restrict__ xm, float* __restrict__ sv) {
  const int c = blockIdx.x, b = blockIdx.y;
  const long base = ((long)(b * CH + c)) * HW;
  const float* p = x + base;
  f16* ph = xh + base;
  f16* pm = xm + base;
  float s = 0.f;
#pragma unroll
  for (int i0 = 0; i0 < 4; ++i0) {
    const int i = (threadIdx.x + i0 * 256) * 4;
    f32x4 v = *(const f32x4*)(p + i);
    half4 h, m;
#pragma unroll
    for (int j = 0; j < 4; ++j) {
      f16 hi = (f16)v[j];
      h[j] = hi;
      m[j] = (f16)(2.f * v[j] - (float)hi);
      s += v[j];
    }
    *(half4*)(ph + i) = h;
    *(half4*)(pm + i) = m;
  }
  s = blockReduce<0>(s);
  if (threadIdx.x == 0) sv[b * CH + c] = s;
}

// xh [B][C][HW] -> xT [B][HW][C]  (f16 transpose via LDS)
__global__ __launch_bounds__(256) void convert2(const f16* __restrict__ xh, f16* __restrict__ xT) {
  const int p0 = blockIdx.x * 64, c0 = blockIdx.y * 64, b = blockIdx.z;
  __shared__ f16 tl[64][72];
  const int t = threadIdx.x;
  const int cr = t >> 2, pc = (t & 3) * 16;
  const f16* src = xh + ((long)(b * CH) + c0 + cr) * HW + p0 + pc;
  half8 a0 = *(const half8*)src, a1 = *(const half8*)(src + 8);
#pragma unroll
  for (int j = 0; j < 8; ++j) {
    tl[pc + j][cr] = a0[j];
    tl[pc + 8 + j][cr] = a1[j];
  }
  __syncthreads();
  f16* dst = xT + ((long)b * HW + p0 + cr) * CH + c0 + pc;
  *(half8*)dst       = *(half8*)&tl[cr][pc];
  *(half8*)(dst + 8) = *(half8*)&tl[cr][pc + 8];
}

// G = (E + E^T)/2 summed over KS partials -> hi/lo f16
template <int KS>
__global__ __launch_bounds__(256) void cvt_g(const float* __restrict__ E, f16* __restrict__ Gh,
                                             f16* __restrict__ Gl) {
  const int c0 = blockIdx.x * 64, r0 = blockIdx.y * 64, b = blockIdx.z;
  __shared__ float tl[64][65];
  const int t = threadIdx.x;
  const int rr0 = t >> 4, c4 = (t & 15) * 4;
  f32x4 acc[4] = {};
  for (int ks = 0; ks < KS; ++ks) {
    const float* Eb = E + ((long)ks * NB + b) * (long)CH * CH;
#pragma unroll
    for (int i = 0; i < 4; ++i)
      acc[i] += *(const f32x4*)(Eb + (long)(r0 + rr0 + i * 16) * CH + c0 + c4);
    __syncthreads();
#pragma unroll
    for (int i = 0; i < 4; ++i) {
      f32x4 w = *(const f32x4*)(Eb + (long)(c0 + rr0 + i * 16) * CH + r0 + c4);
#pragma unroll
      for (int j = 0; j < 4; ++j) tl[rr0 + i * 16][c4 + j] = w[j];
    }
    __syncthreads();
#pragma unroll
    for (int i = 0; i < 4; ++i)
#pragma unroll
      for (int j = 0; j < 4; ++j) acc[i][j] += tl[c4 + j][rr0 + i * 16];
  }
#pragma unroll
  for (int i = 0; i < 4; ++i) {
    half4 h, l;
#pragma unroll
    for (int j = 0; j < 4; ++j) {
      const float g = 0.5f * acc[i][j];
      f16 hi = (f16)g;
      h[j] = hi;
      l[j] = (f16)(g - (float)hi);
    }
    const long oi = ((long)b * CH + r0 + rr0 + i * 16) * CH + c0 + c4;
    *(half4*)(Gh + oi) = h;
    *(half4*)(Gl + oi) = l;
  }
}

__global__ __launch_bounds__(256) void prep_w(const float* __restrict__ w1, const float* __restrict__ w2,
                                              const float* __restrict__ w3, f16* w1h, f16* w1l, f16* w2h,
                                              f16* w2l, f16* w3t) {
  const int i = blockIdx.x * 256 + threadIdx.x;
  if (i >= CH * CH) return;
  float a = w1[i];
  f16 h = (f16)a;
  w1h[i] = h;
  w1l[i] = (f16)(a - (float)h);
  float bv = w2[i];
  h = (f16)bv;
  w2h[i] = h;
  w2l[i] = (f16)(bv - (float)h);
  const int r = i >> 9, c = i & 511;
  w3t[c * CH + r] = (f16)w3[i];
}

__global__ __launch_bounds__(256) void prep_tu(const float* __restrict__ w1, const float* __restrict__ w2,
                                               const float* __restrict__ b2, const float* __restrict__ s,
                                               float* __restrict__ t, float* __restrict__ u) {
  const int b = blockIdx.y, c = blockIdx.x;
  float a1 = 0.f, a2 = 0.f;
  for (int i = threadIdx.x; i < CH; i += 256) {
    float sv = s[b * CH + i];
    a1 += w1[(long)c * CH + i] * sv;
    a2 += w2[(long)c * CH + i] * sv;
  }
  a1 = blockReduce<0>(a1);
  a2 = blockReduce<0>(a2);
  if (threadIdx.x == 0) {
    t[b * CH + c] = a1;
    u[b * CH + c] = a2 + (float)HW * b2[c];
  }
}

__global__ __launch_bounds__(256) void softmax_k(const float* __restrict__ sc, const float* __restrict__ b3,
                                                 f16* __restrict__ attn, float* __restrict__ ab3) {
  const int b = blockIdx.y, c = blockIdx.x;
  const float* row = sc + ((long)(b * CH + c)) * CH;
  const float v0 = row[threadIdx.x], v1 = row[threadIdx.x + 256];
  const float m = blockReduce<1>(fmaxf(v0, v1));
  const float q0 = __expf(v0 - m), q1 = __expf(v1 - m);
  const float sum = blockReduce<0>(q0 + q1);
  const float sb = blockReduce<0>(q0 * b3[threadIdx.x] + q1 * b3[threadIdx.x + 256]);
  const float inv = 1.f / sum;
  attn[((long)(b * CH + c)) * CH + threadIdx.x] = (f16)(q0 * inv);
  attn[((long)(b * CH + c)) * CH + threadIdx.x + 256] = (f16)(q1 * inv);
  if (threadIdx.x == 0) ab3[b * CH + c] = sb * inv;
}

// ---------------- launch ----------------
extern "C" void kernel_launch(void* const* d_in, const int* in_sizes, int n_in, void* d_out, int out_size,
                              void* d_ws, size_t ws_size, hipStream_t stream) {
  const float* x  = (const float*)d_in[0];
  const float* w1 = (const float*)d_in[1];
  const float* b1 = (const float*)d_in[2];
  const float* w2 = (const float*)d_in[3];
  const float* b2 = (const float*)d_in[4];
  const float* w3 = (const float*)d_in[5];
  const float* b3 = (const float*)d_in[6];
  const float* wg = (const float*)d_in[7];
  const float* bg = (const float*)d_in[8];
  float* out = (float*)d_out;

  char* ws = (char*)d_ws;
  size_t off = 0;
  auto alloc = [&](size_t bytes) -> void* {
    void* p = ws + off;
    off += (bytes + 255) & ~(size_t)255;
    return p;
  };
  const long CC = (long)CH * CH;
  const long CHW = (long)CH * HW;
  constexpr int GKS = 4;  // Gram split-K factor
  f16* xh    = (f16*)alloc(NB * CHW * 2);
  f16* xm    = (f16*)alloc(NB * CHW * 2);
  float* Epart = (float*)alloc((long)GKS * NB * CC * 4);
  f16* G16h = (f16*)alloc(NB * CC * 2);
  f16* G16l = (f16*)alloc(NB * CC * 2);
  f16* P16h = (f16*)alloc(NB * CC * 2);
  f16* P16l = (f16*)alloc(NB * CC * 2);
  f16* w1h = (f16*)alloc(CC * 2);
  f16* w1l = (f16*)alloc(CC * 2);
  f16* w2h = (f16*)alloc(CC * 2);
  f16* w2l = (f16*)alloc(CC * 2);
  f16* w3t = (f16*)alloc(CC * 2);
  float* sv = (float*)alloc(NB * CH * 4);
  float* tv = (float*)alloc(NB * CH * 4);
  float* uv = (float*)alloc(NB * CH * 4);
  float* ab3 = (float*)alloc(NB * CH * 4);
  // disjoint-liveness aliases (strictly stream-ordered producer -> consumer):
  f16* xT = (f16*)Epart;                               // Epart dead after cvt_g
  float* scores = (float*)xm;                          // xm dead after Gram (8 MB of 32)
  f16* attn16 = (f16*)((char*)xm + (NB * CC * 4));     // +8 MB, 4 MB
  f16* M16    = (f16*)((char*)xm + (NB * CC * 4) + (NB * CC * 2));  // +12 MB, 4 MB
  // NOTE: xh stays live to the end (gemm_dw dwconv taps).

  const dim3 blk(256);

  prep_w<<<dim3((CH * CH + 255) / 256), blk, 0, stream>>>(w1, w2, w3, w1h, w1l, w2h, w2l, w3t);
  convert1<<<dim3(CH, NB), blk, 0, stream>>>(x, xh, xm, sv);
  prep_tu<<<dim3(CH, NB), blk, 0, stream>>>(w1, w2, b2, sv, tv, uv);

  // E = xh * xm^T, all 16 tile-pairs, split-K4 into per-ks partial buffers
  gemm2<128, 128, false, GKS, 6, 4><<<dim3(4, 4, NB * GKS), blk, 0, stream>>>(
      xh, nullptr, CHW, HW, xm, nullptr, CHW, HW, Epart, nullptr, CC, CH, HW / GKS,
      nullptr, nullptr, nullptr, nullptr);
  // G = (E + E^T)/2, fold KS partials, hi/lo split
  cvt_g<GKS><<<dim3(8, 8, NB), blk, 0, stream>>>(Epart, G16h, G16l);
  // xT = transpose(xh)  (into dead Epart slot)
  convert2<<<dim3(HW / 64, CH / 64, NB), blk, 0, stream>>>(xh, xT);
  // P = W1 * G (split; G symmetric so [n][k] tile == G)
  gemm2<128, 64, true, 1, 0, 3><<<dim3(4, 8, NB), blk, 0, stream>>>(
      w1h, w1l, 0, CH, G16h, G16l, CC, CH, P16h, P16l, CC, CH, CH,
      nullptr, nullptr, nullptr, nullptr);
  // scores = P * W2^T + b1 u^T + t b2^T (split)
  gemm2<128, 64, true, 1, 1, 3><<<dim3(4, 8, NB), blk, 0, stream>>>(
      P16h, P16l, CC, CH, w2h, w2l, 0, CH, scores, nullptr, CC, CH, CH, b1, uv, tv, b2);
  softmax_k<<<dim3(CH, NB), blk, 0, stream>>>(scores, b3, attn16, ab3);
  // M = attn * W3
  gemm2<128, 64, false, 1, 2, 4><<<dim3(4, 8, NB), blk, 0, stream>>>(
      attn16, nullptr, CC, CH, w3t, nullptr, 0, CH, M16, nullptr, CC, CH, CH,
      nullptr, nullptr, nullptr, nullptr);
  // out = x + 0.1*(M x + ab3 + dwconv(xh) + bg)  — fused epilogue, no den16
  gemm_dw<<<dim3(CH / 128, HW / 128, NB), blk, 0, stream>>>(
      M16, xT, xh, x, wg, bg, ab3, out);
}